// Round 4
// baseline (8657.039 us; speedup 1.0000x reference)
//
#include <hip/hip_runtime.h>
#include <math.h>

// Model: S=1024, V=32000, H=1024. Attention is dead code (softmax over a
// size-1 axis == ones), so context = sum_t enc_out[t].
//
// Pipeline (all fp32):
//  1. memsets: zero zerovec; 0xFF sentinel over enc_out & dec_h
//  2. G_enc = embed[input_seq] @ enc_Wih^T + enc_b            (GEMM, MODE1)
//  3. encoder LSTM: persistent 128-WG x 576-thr, poller wave  (lstm_seq)
//  4. ctx_bias = dec_b + dec_Wih[:,H:] @ context              (gemv)
//  5. G_dec = relu(prev) @ dec_Wih[:,:H]^T + ctx_bias         (GEMM, MODE2)
//  6. decoder LSTM                                            (lstm_seq)
//  7. logits = dec_h @ out_w^T + out_b -> d_out               (GEMM, MODE0)
//  8. argmax per row -> d_out[S*V + t]
//
// LSTM sync design: h_out pre-filled with NaN sentinel (0xFF). Producers
// store finite h values agent-scope (straight to LLC). A DEDICATED POLLER
// WAVE (wave 8 of each WG) polls the data itself with L2-bypassing loads
// until NaN-free, stages it to double-buffered LDS, and immediately moves
// on to polling the next step — so LLC poll latency overlaps the compute
// waves' dot/gate work instead of serializing with it. Adaptive ballot
// re-poll: only lanes still seeing NaN re-issue loads (tiny fabric traffic
// after round 1). Finite sigmoid/tanh products can never be NaN.

#define S_LEN 1024
#define HDIM  1024
#define VDIM  32000

typedef float f4 __attribute__((ext_vector_type(4)));

__device__ __forceinline__ void agent_storef(float* p, float v) {
    __hip_atomic_store(p, v, __ATOMIC_RELAXED, __HIP_MEMORY_SCOPE_AGENT);
}
__device__ __forceinline__ float sigmoidf_(float x) {
    return 1.0f / (1.0f + expf(-x));
}
// 4x16B LLC-coherent loads (bypass L1+L2), single waitcnt: one latency, not 4.
__device__ __forceinline__ void llc_load_4x4(const float* p, f4& a, f4& b,
                                             f4& c, f4& d) {
    asm volatile(
        "global_load_dwordx4 %0, %4, off sc0 sc1\n\t"
        "global_load_dwordx4 %1, %4, off offset:1024 sc0 sc1\n\t"
        "global_load_dwordx4 %2, %4, off offset:2048 sc0 sc1\n\t"
        "global_load_dwordx4 %3, %4, off offset:3072 sc0 sc1\n\t"
        "s_waitcnt vmcnt(0)"
        : "=&v"(a), "=&v"(b), "=&v"(c), "=&v"(d)
        : "v"(p) : "memory");
}
__device__ __forceinline__ bool any_nan16(f4 a, f4 b, f4 c, f4 d) {
    float s0 = (a.x + a.y) + (a.z + a.w);
    float s1 = (b.x + b.y) + (b.z + b.w);
    float s2 = (c.x + c.y) + (c.z + c.w);
    float s3 = (d.x + d.y) + (d.z + d.w);
    float s  = (s0 + s1) + (s2 + s3);
    return s != s;
}
// LDS f4-slot swizzle: uniform 8-words/bank for writer (64q+l) and reader
// (lg+64i) access patterns.
__device__ __forceinline__ int swz(int s) {
    return (s & ~7) | ((s ^ (s >> 3)) & 7);
}

// ---------------------------------------------------------------------------
// Tiled NT GEMM: C[M,N] = A_eff(M,K) @ B(N,K)^T + bias[n]
// MODE 0: A_eff = A (lda)
// MODE 1: A_eff[m] = embed[gidx[m]]
// MODE 2: A_eff[0] = 0; A_eff[m] = relu(embed[gidx[m-1]])
// ---------------------------------------------------------------------------
template<int MODE>
__global__ __launch_bounds__(256)
void gemm_nt(const float* __restrict__ A, int lda,
             const float* __restrict__ B, int ldb,
             const float* __restrict__ bias,
             float* __restrict__ C, int ldc,
             const float* __restrict__ embed,
             const int* __restrict__ gidx,
             int M, int N, int K)
{
    __shared__ float As[16][128];
    __shared__ float Bs[16][128];

    const int tid = threadIdx.x;
    const int m0 = blockIdx.y * 128;
    const int n0 = blockIdx.x * 128;

    float acc[8][8];
#pragma unroll
    for (int r = 0; r < 8; ++r)
#pragma unroll
        for (int c = 0; c < 8; ++c) acc[r][c] = 0.0f;

    const int ty = tid >> 4;   // 0..15
    const int tx = tid & 15;   // 0..15

    for (int k0 = 0; k0 < K; k0 += 16) {
#pragma unroll
        for (int q = 0; q < 2; ++q) {
            int id = tid * 2 + q;
            int m  = id >> 2;
            int c4 = (id & 3) * 4;
            float4 v;
            if (MODE == 0) {
                v = *(const float4*)(A + (size_t)(m0 + m) * lda + k0 + c4);
            } else if (MODE == 1) {
                int row = gidx[m0 + m];
                v = *(const float4*)(embed + (size_t)row * HDIM + k0 + c4);
            } else {
                int mg = m0 + m;
                if (mg == 0) {
                    v = make_float4(0.f, 0.f, 0.f, 0.f);
                } else {
                    int row = gidx[mg - 1];
                    v = *(const float4*)(embed + (size_t)row * HDIM + k0 + c4);
                    v.x = fmaxf(v.x, 0.f); v.y = fmaxf(v.y, 0.f);
                    v.z = fmaxf(v.z, 0.f); v.w = fmaxf(v.w, 0.f);
                }
            }
            As[c4 + 0][m] = v.x; As[c4 + 1][m] = v.y;
            As[c4 + 2][m] = v.z; As[c4 + 3][m] = v.w;
        }
#pragma unroll
        for (int q = 0; q < 2; ++q) {
            int id = tid * 2 + q;
            int n  = id >> 2;
            int c4 = (id & 3) * 4;
            float4 v = *(const float4*)(B + (size_t)(n0 + n) * ldb + k0 + c4);
            Bs[c4 + 0][n] = v.x; Bs[c4 + 1][n] = v.y;
            Bs[c4 + 2][n] = v.z; Bs[c4 + 3][n] = v.w;
        }
        __syncthreads();

#pragma unroll
        for (int k = 0; k < 16; ++k) {
            float4 a0 = *(const float4*)&As[k][ty * 8];
            float4 a1 = *(const float4*)&As[k][ty * 8 + 4];
            float4 b0 = *(const float4*)&Bs[k][tx * 8];
            float4 b1 = *(const float4*)&Bs[k][tx * 8 + 4];
            float av[8] = {a0.x,a0.y,a0.z,a0.w,a1.x,a1.y,a1.z,a1.w};
            float bv[8] = {b0.x,b0.y,b0.z,b0.w,b1.x,b1.y,b1.z,b1.w};
#pragma unroll
            for (int r = 0; r < 8; ++r)
#pragma unroll
                for (int c = 0; c < 8; ++c)
                    acc[r][c] = fmaf(av[r], bv[c], acc[r][c]);
        }
        __syncthreads();
    }

    const int mbase = m0 + ty * 8;
    const int nbase = n0 + tx * 8;
#pragma unroll
    for (int r = 0; r < 8; ++r) {
        float4 o0, o1;
        o0.x = acc[r][0] + bias[nbase + 0];
        o0.y = acc[r][1] + bias[nbase + 1];
        o0.z = acc[r][2] + bias[nbase + 2];
        o0.w = acc[r][3] + bias[nbase + 3];
        o1.x = acc[r][4] + bias[nbase + 4];
        o1.y = acc[r][5] + bias[nbase + 5];
        o1.z = acc[r][6] + bias[nbase + 6];
        o1.w = acc[r][7] + bias[nbase + 7];
        *(float4*)(C + (size_t)(mbase + r) * ldc + nbase)     = o0;
        *(float4*)(C + (size_t)(mbase + r) * ldc + nbase + 4) = o1;
    }
}

// ---------------------------------------------------------------------------
// Persistent sequential LSTM, poller-wave + sentinel sync.
// 128 WGs x 576 threads. Wave 8 = dedicated poller; waves 0..7 compute
// h-element j = g*8+wv. Thread (lane lg) of a compute wave holds
// W[4 gates][4 f4] covering k = 4*lg+256*i (64 floats in VGPRs).
// Per step: poller polls h[t-1] (adaptive ballot re-poll, L2-bypass) ->
// swizzled LDS hbuf[t&1] -> barrier; compute waves: barrier -> ds_read ->
// 64 FMA dots -> merged 64-lane butterfly (7 shf) -> gates on lane-classes
// 0..3 -> lane0: c,h update, agent store h. One barrier/step; poll latency
// overlaps compute.
// ---------------------------------------------------------------------------
__global__ __launch_bounds__(576, 1)
void lstm_seq(const float* __restrict__ Whh,
              const float* __restrict__ G,        // (S, 4H) preactivations
              const float* __restrict__ h_init,   // (H), finite values
              const float* __restrict__ c_init,   // (H)
              float* __restrict__ h_out,          // (S, H), pre-filled 0xFF
              float* __restrict__ c_fin,          // (H) or nullptr
              float* __restrict__ csum_out,       // (H) or nullptr
              int slen)
{
    __shared__ f4 hbuf[2][256];                   // 8 KB, double-buffered
    const int tid = threadIdx.x;
    const int g   = blockIdx.x;
    const int wv  = tid >> 6;     // 0..7 compute, 8 = poller
    const int lg  = tid & 63;     // lane in wave

    if (wv == 8) {
        // ------------------------- poller wave -------------------------
        for (int t = 0; t < slen; ++t) {
            const float* hp = (t == 0) ? h_init
                                       : (h_out + (size_t)(t - 1) * HDIM);
            const float* p = hp + 4 * lg;
            f4 a, b, c2, d;
            llc_load_4x4(p, a, b, c2, d);
            bool bad = any_nan16(a, b, c2, d);
            while (__any(bad)) {
                if (bad) {                        // exec-masked re-poll
                    llc_load_4x4(p, a, b, c2, d);
                    bad = any_nan16(a, b, c2, d);
                }
            }
            f4* hb = hbuf[t & 1];
            hb[swz(lg)]       = a;
            hb[swz(64 + lg)]  = b;
            hb[swz(128 + lg)] = c2;
            hb[swz(192 + lg)] = d;
            __syncthreads();                      // release stage t
        }
        return;
    }

    // ------------------------- compute waves -------------------------
    const int j = g * 8 + wv;

    // W[q][i] = Whh[j + q*H, 4*lg + 256*i .. +3]  (coalesced f4 loads)
    f4 W[4][4];
#pragma unroll
    for (int q = 0; q < 4; ++q)
#pragma unroll
        for (int i = 0; i < 4; ++i)
            W[q][i] = *(const f4*)(Whh + (size_t)(j + q * HDIM) * HDIM
                                   + 4 * lg + 256 * i);

    float c = 0.0f, csum = 0.0f;
    if (lg == 0) c = c_init[j];

    // gate preactivation for class (lg&3), prefetched one step ahead
    float gnow = G[(size_t)(lg & 3) * HDIM + j];

    for (int t = 0; t < slen; ++t) {
        __syncthreads();                          // wait for stage t

        const f4* hb = hbuf[t & 1];
        f4 h0 = hb[swz(lg)];
        f4 h1 = hb[swz(64 + lg)];
        f4 h2 = hb[swz(128 + lg)];
        f4 h3 = hb[swz(192 + lg)];

        // prefetch next step's G value (hidden behind this step's compute)
        int tn = (t + 1 < slen) ? (t + 1) : t;
        float gnext = G[(size_t)tn * (4 * HDIM) + (lg & 3) * HDIM + j];

        // 4 gate dot-products: 64 FMA per lane
        float p0 = 0.f, p1 = 0.f, p2 = 0.f, p3 = 0.f;
        f4 hv;
#pragma unroll
        for (int i = 0; i < 4; ++i) {
            hv = (i == 0) ? h0 : (i == 1) ? h1 : (i == 2) ? h2 : h3;
            p0 = fmaf(W[0][i].x, hv.x, fmaf(W[0][i].y, hv.y,
                 fmaf(W[0][i].z, hv.z, fmaf(W[0][i].w, hv.w, p0))));
            p1 = fmaf(W[1][i].x, hv.x, fmaf(W[1][i].y, hv.y,
                 fmaf(W[1][i].z, hv.z, fmaf(W[1][i].w, hv.w, p1))));
            p2 = fmaf(W[2][i].x, hv.x, fmaf(W[2][i].y, hv.y,
                 fmaf(W[2][i].z, hv.z, fmaf(W[2][i].w, hv.w, p2))));
            p3 = fmaf(W[3][i].x, hv.x, fmaf(W[3][i].y, hv.y,
                 fmaf(W[3][i].z, hv.z, fmaf(W[3][i].w, hv.w, p3))));
        }

        // merged butterfly over 64 lanes: class (lg&3) ends with gate (lg&3)
        float t01 = __shfl_xor((lg & 1) ? p0 : p1, 1);
        float s01 = ((lg & 1) ? p1 : p0) + t01;
        float t23 = __shfl_xor((lg & 1) ? p2 : p3, 1);
        float s23 = ((lg & 1) ? p3 : p2) + t23;
        float tq  = __shfl_xor((lg & 2) ? s01 : s23, 2);
        float s   = ((lg & 2) ? s23 : s01) + tq;
        s += __shfl_xor(s, 4);
        s += __shfl_xor(s, 8);
        s += __shfl_xor(s, 16);
        s += __shfl_xor(s, 32);

        // gate activations on lane-classes (i,f,g,o) = classes (0,1,2,3)
        float pre = s + gnow;
        float act = ((lg & 3) == 2) ? tanhf(pre) : sigmoidf_(pre);
        float a1 = __shfl(act, 1);   // sigmoid(f)
        float a2 = __shfl(act, 2);   // tanh(g)
        float a3 = __shfl(act, 3);   // sigmoid(o)

        if (lg == 0) {
            c = a1 * c + act * a2;          // act == sigmoid(i) on lane 0
            float h = a3 * tanhf(c);
            csum += h;
            agent_storef(h_out + (size_t)t * HDIM + j, h);
        }
        gnow = gnext;
    }

    if (lg == 0) {
        if (c_fin)    c_fin[j]    = c;
        if (csum_out) csum_out[j] = csum;
    }
}

// ctx_bias[r] = dec_b[r] + dot(dec_Wih[r, H:2H], context)
__global__ __launch_bounds__(256)
void ctx_bias_k(const float* __restrict__ dec_Wih,
                const float* __restrict__ dec_b,
                const float* __restrict__ ctx,
                float* __restrict__ out)
{
    const int wv = threadIdx.x >> 6;
    const int lane = threadIdx.x & 63;
    const int r = blockIdx.x * 4 + wv;      // grid 1024 -> r in [0,4096)
    const float* wr = dec_Wih + (size_t)r * (2 * HDIM) + HDIM;
    float s = 0.f;
    for (int k = lane; k < HDIM; k += 64) s += wr[k] * ctx[k];
#pragma unroll
    for (int off = 32; off > 0; off >>= 1) s += __shfl_xor(s, off);
    if (lane == 0) out[r] = s + dec_b[r];
}

// per-row argmax (numpy tie rule: first index)
__global__ __launch_bounds__(256)
void argmax_k(const float* __restrict__ logits, float* __restrict__ out_idx)
{
    __shared__ float bv[256];
    __shared__ int   bidx[256];
    const int row = blockIdx.x;
    const int tid = threadIdx.x;
    const float* p = logits + (size_t)row * VDIM;
    float best = -INFINITY;
    int   bi   = 0;
    for (int v = tid; v < VDIM; v += 256) {
        float x = p[v];
        if (x > best) { best = x; bi = v; }   // strictly greater keeps first
    }
    bv[tid] = best; bidx[tid] = bi;
    __syncthreads();
    for (int s = 128; s > 0; s >>= 1) {
        if (tid < s) {
            if (bv[tid + s] > bv[tid] ||
                (bv[tid + s] == bv[tid] && bidx[tid + s] < bidx[tid])) {
                bv[tid] = bv[tid + s];
                bidx[tid] = bidx[tid + s];
            }
        }
        __syncthreads();
    }
    if (tid == 0) out_idx[row] = (float)bidx[0];
}

extern "C" void kernel_launch(void* const* d_in, const int* in_sizes, int n_in,
                              void* d_out, int out_size, void* d_ws, size_t ws_size,
                              hipStream_t stream)
{
    (void)in_sizes; (void)n_in; (void)out_size; (void)ws_size;

    const int*   input_seq = (const int*)d_in[0];
    const int*   gold_seq  = (const int*)d_in[1];
    const float* embed     = (const float*)d_in[2];
    const float* enc_Wih   = (const float*)d_in[3];
    const float* enc_Whh   = (const float*)d_in[4];
    const float* enc_b     = (const float*)d_in[5];
    const float* dec_Wih   = (const float*)d_in[6];
    const float* dec_Whh   = (const float*)d_in[7];
    const float* dec_b     = (const float*)d_in[8];
    // d_in[9..14]: attention params — dead code (softmax over size-1 axis)
    const float* out_w     = (const float*)d_in[15];
    const float* out_b     = (const float*)d_in[16];

    float* out = (float*)d_out;

    // d_out doubles as scratch for G matrices (overwritten by logits GEMM later)
    float* G_enc = out;                 // S*4H = 4,194,304 floats
    float* G_dec = out + 4194304;       // S*4H

    // workspace layout
    float* zerovec   = (float*)d_ws + 256;   // 1024
    float* c0        = zerovec + 1024;       // 1024
    float* ctx       = c0 + 1024;            // 1024
    float* ctxb      = ctx + 1024;           // 4096
    float* enc_out   = ctxb + 4096;          // S*H = 1,048,576
    float* dec_h     = enc_out + 1048576;    // S*H

    // zero zerovec region; NaN-sentinel both h buffers
    hipMemsetAsync(d_ws, 0, 5120, stream);
    hipMemsetAsync(enc_out, 0xFF, (size_t)S_LEN * HDIM * 4, stream);
    hipMemsetAsync(dec_h,   0xFF, (size_t)S_LEN * HDIM * 4, stream);

    dim3 blk(256);

    // G_enc = embed[input_seq] @ enc_Wih^T + enc_b
    gemm_nt<1><<<dim3(32, 8), blk, 0, stream>>>(
        nullptr, 0, enc_Wih, HDIM, enc_b, G_enc, 4 * HDIM,
        embed, input_seq, S_LEN, 4 * HDIM, HDIM);

    // encoder
    lstm_seq<<<128, dim3(576), 0, stream>>>(
        enc_Whh, G_enc, zerovec, zerovec, enc_out, c0, ctx, S_LEN);

    // decoder constant bias: dec_b + dec_Wih[:,H:] @ ctx
    ctx_bias_k<<<1024, blk, 0, stream>>>(dec_Wih, dec_b, ctx, ctxb);

    // G_dec = relu(prev) @ dec_Wih[:,:H]^T + ctxb
    gemm_nt<2><<<dim3(32, 8), blk, 0, stream>>>(
        nullptr, 0, dec_Wih, 2 * HDIM, ctxb, G_dec, 4 * HDIM,
        embed, gold_seq, S_LEN, 4 * HDIM, HDIM);

    // decoder (h_init = encoder's final h, already finite values)
    lstm_seq<<<128, dim3(576), 0, stream>>>(
        dec_Whh, G_dec, enc_out + (size_t)(S_LEN - 1) * HDIM, c0,
        dec_h, nullptr, nullptr, S_LEN);

    // logits = dec_h @ out_w^T + out_b  -> d_out[0 : S*V)
    gemm_nt<0><<<dim3(VDIM / 128, 8), blk, 0, stream>>>(
        dec_h, HDIM, out_w, HDIM, out_b, out, VDIM,
        nullptr, nullptr, S_LEN, VDIM, HDIM);

    // idxs -> d_out[S*V : S*V + S)
    argmax_k<<<1024, blk, 0, stream>>>(out, out + (size_t)S_LEN * VDIM);
}

// Round 5
// 5334.606 us; speedup vs baseline: 1.6228x; 1.6228x over previous
//
#include <hip/hip_runtime.h>
#include <math.h>

// Model: S=1024, V=32000, H=1024. Attention is dead code (softmax over a
// size-1 axis == ones), so context = sum_t enc_out[t].
//
// Pipeline (all fp32):
//  1. memsets: zero zerovec; 0xFF sentinel over enc_out & dec_h
//  2. G_enc = embed[input_seq] @ enc_Wih^T + enc_b            (GEMM, MODE1)
//  3. encoder LSTM: persistent 128-WG x 512-thr, sentinel-poll (lstm_seq)
//  4. ctx_bias = dec_b + dec_Wih[:,H:] @ context              (gemv)
//  5. G_dec = relu(prev) @ dec_Wih[:,:H]^T + ctx_bias         (GEMM, MODE2)
//  6. decoder LSTM                                            (lstm_seq)
//  7. logits = dec_h @ out_w^T + out_b -> d_out               (GEMM, MODE0)
//  8. argmax per row -> d_out[S*V + t]
//
// LSTM sync (round-3 proven): h_out pre-filled with NaN sentinel (0xFF).
// Producers store finite h agent-scope (straight to LLC). Wave 0 of each WG
// polls the data itself with L2-bypassing loads until NaN-free (s_sleep(1)
// throttled — round 4 showed hot-spin congests the fabric and doubles
// latency), stages to LDS. Finite sigmoid/tanh products can never be NaN.
//
// Round-5 delta vs round 3: W[4][4] is pinned into VGPRs with empty-asm
// "+v" ties each iteration. Round 3's VGPR_Count=60 < 64 W-floats proved the
// compiler was re-streaming each WG's 128 KB Whh slice from L2 every step
// (~2 MB/XCD/step ≈ 1100 cy of L2 BW) — the pin forces true residency.

#define S_LEN 1024
#define HDIM  1024
#define VDIM  32000

typedef float f4 __attribute__((ext_vector_type(4)));

__device__ __forceinline__ void agent_storef(float* p, float v) {
    __hip_atomic_store(p, v, __ATOMIC_RELAXED, __HIP_MEMORY_SCOPE_AGENT);
}
__device__ __forceinline__ float sigmoidf_(float x) {
    return 1.0f / (1.0f + expf(-x));
}
// 4x16B LLC-coherent loads (bypass L1+L2), single waitcnt: one latency, not 4.
__device__ __forceinline__ void llc_load_4x4(const float* p, f4& a, f4& b,
                                             f4& c, f4& d) {
    asm volatile(
        "global_load_dwordx4 %0, %4, off sc0 sc1\n\t"
        "global_load_dwordx4 %1, %4, off offset:1024 sc0 sc1\n\t"
        "global_load_dwordx4 %2, %4, off offset:2048 sc0 sc1\n\t"
        "global_load_dwordx4 %3, %4, off offset:3072 sc0 sc1\n\t"
        "s_waitcnt vmcnt(0)"
        : "=&v"(a), "=&v"(b), "=&v"(c), "=&v"(d)
        : "v"(p) : "memory");
}
// LDS f4-slot swizzle: uniform 8-words/bank for writer (64q+l) and reader
// (lg+64i) access patterns.
__device__ __forceinline__ int swz(int s) {
    return (s & ~7) | ((s ^ (s >> 3)) & 7);
}

// ---------------------------------------------------------------------------
// Tiled NT GEMM: C[M,N] = A_eff(M,K) @ B(N,K)^T + bias[n]
// MODE 0: A_eff = A (lda)
// MODE 1: A_eff[m] = embed[gidx[m]]
// MODE 2: A_eff[0] = 0; A_eff[m] = relu(embed[gidx[m-1]])
// ---------------------------------------------------------------------------
template<int MODE>
__global__ __launch_bounds__(256)
void gemm_nt(const float* __restrict__ A, int lda,
             const float* __restrict__ B, int ldb,
             const float* __restrict__ bias,
             float* __restrict__ C, int ldc,
             const float* __restrict__ embed,
             const int* __restrict__ gidx,
             int M, int N, int K)
{
    __shared__ float As[16][128];
    __shared__ float Bs[16][128];

    const int tid = threadIdx.x;
    const int m0 = blockIdx.y * 128;
    const int n0 = blockIdx.x * 128;

    float acc[8][8];
#pragma unroll
    for (int r = 0; r < 8; ++r)
#pragma unroll
        for (int c = 0; c < 8; ++c) acc[r][c] = 0.0f;

    const int ty = tid >> 4;   // 0..15
    const int tx = tid & 15;   // 0..15

    for (int k0 = 0; k0 < K; k0 += 16) {
#pragma unroll
        for (int q = 0; q < 2; ++q) {
            int id = tid * 2 + q;
            int m  = id >> 2;
            int c4 = (id & 3) * 4;
            float4 v;
            if (MODE == 0) {
                v = *(const float4*)(A + (size_t)(m0 + m) * lda + k0 + c4);
            } else if (MODE == 1) {
                int row = gidx[m0 + m];
                v = *(const float4*)(embed + (size_t)row * HDIM + k0 + c4);
            } else {
                int mg = m0 + m;
                if (mg == 0) {
                    v = make_float4(0.f, 0.f, 0.f, 0.f);
                } else {
                    int row = gidx[mg - 1];
                    v = *(const float4*)(embed + (size_t)row * HDIM + k0 + c4);
                    v.x = fmaxf(v.x, 0.f); v.y = fmaxf(v.y, 0.f);
                    v.z = fmaxf(v.z, 0.f); v.w = fmaxf(v.w, 0.f);
                }
            }
            As[c4 + 0][m] = v.x; As[c4 + 1][m] = v.y;
            As[c4 + 2][m] = v.z; As[c4 + 3][m] = v.w;
        }
#pragma unroll
        for (int q = 0; q < 2; ++q) {
            int id = tid * 2 + q;
            int n  = id >> 2;
            int c4 = (id & 3) * 4;
            float4 v = *(const float4*)(B + (size_t)(n0 + n) * ldb + k0 + c4);
            Bs[c4 + 0][n] = v.x; Bs[c4 + 1][n] = v.y;
            Bs[c4 + 2][n] = v.z; Bs[c4 + 3][n] = v.w;
        }
        __syncthreads();

#pragma unroll
        for (int k = 0; k < 16; ++k) {
            float4 a0 = *(const float4*)&As[k][ty * 8];
            float4 a1 = *(const float4*)&As[k][ty * 8 + 4];
            float4 b0 = *(const float4*)&Bs[k][tx * 8];
            float4 b1 = *(const float4*)&Bs[k][tx * 8 + 4];
            float av[8] = {a0.x,a0.y,a0.z,a0.w,a1.x,a1.y,a1.z,a1.w};
            float bv[8] = {b0.x,b0.y,b0.z,b0.w,b1.x,b1.y,b1.z,b1.w};
#pragma unroll
            for (int r = 0; r < 8; ++r)
#pragma unroll
                for (int c = 0; c < 8; ++c)
                    acc[r][c] = fmaf(av[r], bv[c], acc[r][c]);
        }
        __syncthreads();
    }

    const int mbase = m0 + ty * 8;
    const int nbase = n0 + tx * 8;
#pragma unroll
    for (int r = 0; r < 8; ++r) {
        float4 o0, o1;
        o0.x = acc[r][0] + bias[nbase + 0];
        o0.y = acc[r][1] + bias[nbase + 1];
        o0.z = acc[r][2] + bias[nbase + 2];
        o0.w = acc[r][3] + bias[nbase + 3];
        o1.x = acc[r][4] + bias[nbase + 4];
        o1.y = acc[r][5] + bias[nbase + 5];
        o1.z = acc[r][6] + bias[nbase + 6];
        o1.w = acc[r][7] + bias[nbase + 7];
        *(float4*)(C + (size_t)(mbase + r) * ldc + nbase)     = o0;
        *(float4*)(C + (size_t)(mbase + r) * ldc + nbase + 4) = o1;
    }
}

// ---------------------------------------------------------------------------
// Persistent sequential LSTM, sentinel-poll sync. 128 WGs x 512 threads.
// Wave wv of WG g owns h-element j = g*8+wv. Thread (lane lg) holds
// W[4 gates][4 f4] covering k = 4*lg+256*i (64 floats), PINNED in VGPRs
// via per-iteration empty-asm "+v" ties.
// Per step:
//   wave0: poll 4KB h_prev via 4 bypass dwordx4 until no NaN -> swizzled LDS
//   sync | all: read 4 f4 from LDS, 64 FMA | merged 64-lane butterfly (7 shf)
//   gates on lane-classes 0..3 | lane0: c,h update, agent store h | sync
// ---------------------------------------------------------------------------
__global__ __launch_bounds__(512, 2)
void lstm_seq(const float* __restrict__ Whh,
              const float* __restrict__ G,        // (S, 4H) preactivations
              const float* __restrict__ h_init,   // (H), finite values
              const float* __restrict__ c_init,   // (H)
              float* __restrict__ h_out,          // (S, H), pre-filled 0xFF
              float* __restrict__ c_fin,          // (H) or nullptr
              float* __restrict__ csum_out,       // (H) or nullptr
              int slen)
{
    __shared__ f4 hbuf[256];                      // 4 KB, swizzled slots
    const int tid = threadIdx.x;
    const int g   = blockIdx.x;
    const int wv  = tid >> 6;     // 0..7 : h-element index within WG
    const int lg  = tid & 63;     // lane in wave
    const int j   = g * 8 + wv;

    // W[q][i] = Whh[j + q*H, 4*lg + 256*i .. +3]  (coalesced f4 loads)
    f4 W[4][4];
#pragma unroll
    for (int q = 0; q < 4; ++q)
#pragma unroll
        for (int i = 0; i < 4; ++i)
            W[q][i] = *(const f4*)(Whh + (size_t)(j + q * HDIM) * HDIM
                                   + 4 * lg + 256 * i);

    float c = 0.0f, csum = 0.0f;
    if (lg == 0) c = c_init[j];

    // gate preactivation for class (lg&3), prefetched one step ahead
    float gnow = G[(size_t)(lg & 3) * HDIM + j];

    for (int t = 0; t < slen; ++t) {
        // pin W in VGPRs: the asm "modifies" each value, so the compiler
        // cannot re-load it from memory inside the loop (round 3 streamed
        // 128 KB/WG/step from L2 without this).
#pragma unroll
        for (int q = 0; q < 4; ++q)
#pragma unroll
            for (int i = 0; i < 4; ++i)
                asm volatile("" : "+v"(W[q][i]));

        const float* hp = (t == 0) ? h_init : (h_out + (size_t)(t - 1) * HDIM);

        if (wv == 0) {
            // poll h_prev until all 16 values are non-NaN (sentinel cleared)
            f4 a, b, cc, d;
            const float* p = hp + 4 * lg;
            for (;;) {
                llc_load_4x4(p, a, b, cc, d);
                float s0 = (a.x + a.y) + (a.z + a.w);
                float s1 = (b.x + b.y) + (b.z + b.w);
                float s2 = (cc.x + cc.y) + (cc.z + cc.w);
                float s3 = (d.x + d.y) + (d.z + d.w);
                float s  = (s0 + s1) + (s2 + s3);
                if (!__any(s != s)) break;
                __builtin_amdgcn_s_sleep(1);
            }
            hbuf[swz(lg)]       = a;
            hbuf[swz(64 + lg)]  = b;
            hbuf[swz(128 + lg)] = cc;
            hbuf[swz(192 + lg)] = d;
        }
        __syncthreads();

        // prefetch next step's G value (hidden behind this step's compute)
        int tn = (t + 1 < slen) ? (t + 1) : t;
        float gnext = G[(size_t)tn * (4 * HDIM) + (lg & 3) * HDIM + j];

        // 4 gate dot-products: 64 FMA per lane
        f4 h0 = hbuf[swz(lg)];
        f4 h1 = hbuf[swz(64 + lg)];
        f4 h2 = hbuf[swz(128 + lg)];
        f4 h3 = hbuf[swz(192 + lg)];
        float p0 = 0.f, p1 = 0.f, p2 = 0.f, p3 = 0.f;
        f4 hv;
#pragma unroll
        for (int i = 0; i < 4; ++i) {
            hv = (i == 0) ? h0 : (i == 1) ? h1 : (i == 2) ? h2 : h3;
            p0 = fmaf(W[0][i].x, hv.x, fmaf(W[0][i].y, hv.y,
                 fmaf(W[0][i].z, hv.z, fmaf(W[0][i].w, hv.w, p0))));
            p1 = fmaf(W[1][i].x, hv.x, fmaf(W[1][i].y, hv.y,
                 fmaf(W[1][i].z, hv.z, fmaf(W[1][i].w, hv.w, p1))));
            p2 = fmaf(W[2][i].x, hv.x, fmaf(W[2][i].y, hv.y,
                 fmaf(W[2][i].z, hv.z, fmaf(W[2][i].w, hv.w, p2))));
            p3 = fmaf(W[3][i].x, hv.x, fmaf(W[3][i].y, hv.y,
                 fmaf(W[3][i].z, hv.z, fmaf(W[3][i].w, hv.w, p3))));
        }

        // merged butterfly over 64 lanes: class (lg&3) ends with gate (lg&3)
        float t01 = __shfl_xor((lg & 1) ? p0 : p1, 1);
        float s01 = ((lg & 1) ? p1 : p0) + t01;
        float t23 = __shfl_xor((lg & 1) ? p2 : p3, 1);
        float s23 = ((lg & 1) ? p3 : p2) + t23;
        float tq  = __shfl_xor((lg & 2) ? s01 : s23, 2);
        float s   = ((lg & 2) ? s23 : s01) + tq;
        s += __shfl_xor(s, 4);
        s += __shfl_xor(s, 8);
        s += __shfl_xor(s, 16);
        s += __shfl_xor(s, 32);

        // gate activations on lane-classes (i,f,g,o) = classes (0,1,2,3)
        float pre = s + gnow;
        float act = ((lg & 3) == 2) ? tanhf(pre) : sigmoidf_(pre);
        float a1 = __shfl(act, 1);   // sigmoid(f)
        float a2 = __shfl(act, 2);   // tanh(g)
        float a3 = __shfl(act, 3);   // sigmoid(o)

        if (lg == 0) {
            c = a1 * c + act * a2;          // act == sigmoid(i) on lane 0
            float h = a3 * tanhf(c);
            csum += h;
            agent_storef(h_out + (size_t)t * HDIM + j, h);
        }
        gnow = gnext;

        __syncthreads();   // protect hbuf before next step's wave0 overwrite
    }

    if (lg == 0) {
        if (c_fin)    c_fin[j]    = c;
        if (csum_out) csum_out[j] = csum;
    }
}

// ctx_bias[r] = dec_b[r] + dot(dec_Wih[r, H:2H], context)
__global__ __launch_bounds__(256)
void ctx_bias_k(const float* __restrict__ dec_Wih,
                const float* __restrict__ dec_b,
                const float* __restrict__ ctx,
                float* __restrict__ out)
{
    const int wv = threadIdx.x >> 6;
    const int lane = threadIdx.x & 63;
    const int r = blockIdx.x * 4 + wv;      // grid 1024 -> r in [0,4096)
    const float* wr = dec_Wih + (size_t)r * (2 * HDIM) + HDIM;
    float s = 0.f;
    for (int k = lane; k < HDIM; k += 64) s += wr[k] * ctx[k];
#pragma unroll
    for (int off = 32; off > 0; off >>= 1) s += __shfl_xor(s, off);
    if (lane == 0) out[r] = s + dec_b[r];
}

// per-row argmax (numpy tie rule: first index)
__global__ __launch_bounds__(256)
void argmax_k(const float* __restrict__ logits, float* __restrict__ out_idx)
{
    __shared__ float bv[256];
    __shared__ int   bidx[256];
    const int row = blockIdx.x;
    const int tid = threadIdx.x;
    const float* p = logits + (size_t)row * VDIM;
    float best = -INFINITY;
    int   bi   = 0;
    for (int v = tid; v < VDIM; v += 256) {
        float x = p[v];
        if (x > best) { best = x; bi = v; }   // strictly greater keeps first
    }
    bv[tid] = best; bidx[tid] = bi;
    __syncthreads();
    for (int s = 128; s > 0; s >>= 1) {
        if (tid < s) {
            if (bv[tid + s] > bv[tid] ||
                (bv[tid + s] == bv[tid] && bidx[tid + s] < bidx[tid])) {
                bv[tid] = bv[tid + s];
                bidx[tid] = bidx[tid + s];
            }
        }
        __syncthreads();
    }
    if (tid == 0) out_idx[row] = (float)bidx[0];
}

extern "C" void kernel_launch(void* const* d_in, const int* in_sizes, int n_in,
                              void* d_out, int out_size, void* d_ws, size_t ws_size,
                              hipStream_t stream)
{
    (void)in_sizes; (void)n_in; (void)out_size; (void)ws_size;

    const int*   input_seq = (const int*)d_in[0];
    const int*   gold_seq  = (const int*)d_in[1];
    const float* embed     = (const float*)d_in[2];
    const float* enc_Wih   = (const float*)d_in[3];
    const float* enc_Whh   = (const float*)d_in[4];
    const float* enc_b     = (const float*)d_in[5];
    const float* dec_Wih   = (const float*)d_in[6];
    const float* dec_Whh   = (const float*)d_in[7];
    const float* dec_b     = (const float*)d_in[8];
    // d_in[9..14]: attention params — dead code (softmax over size-1 axis)
    const float* out_w     = (const float*)d_in[15];
    const float* out_b     = (const float*)d_in[16];

    float* out = (float*)d_out;

    // d_out doubles as scratch for G matrices (overwritten by logits GEMM later)
    float* G_enc = out;                 // S*4H = 4,194,304 floats
    float* G_dec = out + 4194304;       // S*4H

    // workspace layout
    float* zerovec   = (float*)d_ws + 256;   // 1024
    float* c0        = zerovec + 1024;       // 1024
    float* ctx       = c0 + 1024;            // 1024
    float* ctxb      = ctx + 1024;           // 4096
    float* enc_out   = ctxb + 4096;          // S*H = 1,048,576
    float* dec_h     = enc_out + 1048576;    // S*H

    // zero zerovec region; NaN-sentinel both h buffers
    hipMemsetAsync(d_ws, 0, 5120, stream);
    hipMemsetAsync(enc_out, 0xFF, (size_t)S_LEN * HDIM * 4, stream);
    hipMemsetAsync(dec_h,   0xFF, (size_t)S_LEN * HDIM * 4, stream);

    dim3 blk(256);

    // G_enc = embed[input_seq] @ enc_Wih^T + enc_b
    gemm_nt<1><<<dim3(32, 8), blk, 0, stream>>>(
        nullptr, 0, enc_Wih, HDIM, enc_b, G_enc, 4 * HDIM,
        embed, input_seq, S_LEN, 4 * HDIM, HDIM);

    // encoder
    lstm_seq<<<128, dim3(512), 0, stream>>>(
        enc_Whh, G_enc, zerovec, zerovec, enc_out, c0, ctx, S_LEN);

    // decoder constant bias: dec_b + dec_Wih[:,H:] @ ctx
    ctx_bias_k<<<1024, blk, 0, stream>>>(dec_Wih, dec_b, ctx, ctxb);

    // G_dec = relu(prev) @ dec_Wih[:,:H]^T + ctxb
    gemm_nt<2><<<dim3(32, 8), blk, 0, stream>>>(
        nullptr, 0, dec_Wih, 2 * HDIM, ctxb, G_dec, 4 * HDIM,
        embed, gold_seq, S_LEN, 4 * HDIM, HDIM);

    // decoder (h_init = encoder's final h, already finite values)
    lstm_seq<<<128, dim3(512), 0, stream>>>(
        dec_Whh, G_dec, enc_out + (size_t)(S_LEN - 1) * HDIM, c0,
        dec_h, nullptr, nullptr, S_LEN);

    // logits = dec_h @ out_w^T + out_b  -> d_out[0 : S*V)
    gemm_nt<0><<<dim3(VDIM / 128, 8), blk, 0, stream>>>(
        dec_h, HDIM, out_w, HDIM, out_b, out, VDIM,
        nullptr, nullptr, S_LEN, VDIM, HDIM);

    // idxs -> d_out[S*V : S*V + S)
    argmax_k<<<1024, blk, 0, stream>>>(out, out + (size_t)S_LEN * VDIM);
}